// Round 1
// 468.649 us; speedup vs baseline: 1.0347x; 1.0347x over previous
//
#include <hip/hip_runtime.h>

#define F 128
#define PAIRS_PER_BLOCK 32   // edge kernel: 32 pairs/block, 4 per half-wave

typedef __attribute__((ext_vector_type(8))) short bf16x8;   // 8 bf16 = 4 VGPRs
typedef __attribute__((ext_vector_type(4))) float f32x4;    // MFMA accumulator

// fp32 -> bf16 round-to-nearest-even (inputs are normal floats here)
static __device__ __forceinline__ unsigned short f2bf(float f) {
    unsigned int u = __float_as_uint(f);
    u += 0x7FFFu + ((u >> 16) & 1u);
    return (unsigned short)(u >> 16);
}
static __device__ __forceinline__ float bf2f(unsigned short h) {
    return __uint_as_float(((unsigned int)h) << 16);
}

// ---------------------------------------------------------------------------
// Phase 0: convert Wq/Wk (FxF fp32, row-major [k][n]) into bf16 hi/lo split,
// TRANSPOSED to [n][k] with XOR-swizzled k (element k ^ ((n&7)<<3), 16-B
// granules preserved) so proj can linear-copy into LDS and read B-fragments
// with conflict-free ds_read_b128. Runs once, ~130 KB of traffic.
// Layout in wt: [sel(q=0,k=1)] x { hi[16384], lo[16384] } shorts.
// ---------------------------------------------------------------------------
__global__ __launch_bounds__(256) void prep_w(
    const float* __restrict__ Wq,
    const float* __restrict__ Wk,
    unsigned short* __restrict__ wt)
{
    const int gid = blockIdx.x * 256 + threadIdx.x;   // 0..32767
    const int sel = gid >> 14;
    const int e   = gid & 16383;
    const int kk  = e >> 7;      // input-feature index (contraction dim)
    const int n   = e & 127;     // output-feature index
    const float v = (sel ? Wk : Wq)[e];
    const unsigned short hi = f2bf(v);
    const unsigned short lo = f2bf(v - bf2f(hi));
    const int idx = n * F + (kk ^ ((n & 7) << 3));    // swizzled short index
    unsigned short* base = wt + sel * 32768;
    base[idx]         = hi;
    base[16384 + idx] = lo;
}

// ---------------------------------------------------------------------------
// Phase 1: q = x @ Wq, k = x @ Wk via bf16 MFMA 16x16x32, hi/lo split
// (x_hi*W_hi + x_hi*W_lo + x_lo*W_hi, fp32 accum -> error ~1e-5 rel, well
// below the bf16 output store that dominated absmax before).
// Block = 256 thr (4 waves as 2x2), tile 64 rows x 128 cols. LDS = 64 KB
// (pre-swizzled W hi/lo) -> 2 blocks/CU. x fragments loaded from global:
// per wave-instr 16 rows x 32 B (rows contiguous across k-loop -> 128-B runs).
// A-frag layout: row = lane&15, k = 8*(lane>>4)+e  (k-permutation applied
// identically to A and B, so contraction is invariant to the exact HW k-map).
// C/D layout (verified): col = lane&15, row = 4*(lane>>4)+reg.
// ---------------------------------------------------------------------------
__global__ __launch_bounds__(256) void proj_mfma(
    const float* __restrict__ x,
    const unsigned short* __restrict__ wt,
    unsigned short* __restrict__ q,
    unsigned short* __restrict__ k)
{
    __shared__ unsigned short lds_w[2 * 16384];   // 64 KB: hi then lo

    const int t   = threadIdx.x;
    const int isK = blockIdx.y;
    const unsigned short* __restrict__ wsrc = wt + (size_t)isK * 32768;
    unsigned short* __restrict__ outp = isK ? k : q;

    // linear 64 KB copy (swizzle is baked into the global image)
    {
        const int4* src = (const int4*)wsrc;
        int4* dst = (int4*)lds_w;
        #pragma unroll
        for (int i = 0; i < 16; ++i) dst[i * 256 + t] = src[i * 256 + t];
    }
    __syncthreads();

    const int w     = t >> 6;              // wave 0..3
    const int l     = t & 63;
    const int l15   = l & 15;
    const int lg    = l >> 4;              // 0..3
    const int rbase = blockIdx.x * 64 + (w >> 1) * 32;   // wave: 32 rows
    const int cbase = (w & 1) * 64;                      // wave: 64 cols

    f32x4 acc[2][4] = {};

    #pragma unroll
    for (int ks = 0; ks < 4; ++ks) {
        // A fragments: 2 row-tiles, hi+lo, straight from global
        bf16x8 ahi[2], alo[2];
        #pragma unroll
        for (int rt = 0; rt < 2; ++rt) {
            const float* xp = x + (size_t)(rbase + rt * 16 + l15) * F + ks * 32 + lg * 8;
            const float4 v0 = *(const float4*)xp;
            const float4 v1 = *(const float4*)(xp + 4);
            const float vv[8] = {v0.x, v0.y, v0.z, v0.w, v1.x, v1.y, v1.z, v1.w};
            #pragma unroll
            for (int e = 0; e < 8; ++e) {
                const unsigned short h = f2bf(vv[e]);
                ahi[rt][e] = (short)h;
                alo[rt][e] = (short)f2bf(vv[e] - bf2f(h));
            }
        }
        // B fragments: 4 col-tiles, hi+lo, swizzled ds_read_b128 (~2-way max)
        bf16x8 bhi[4], blo[4];
        #pragma unroll
        for (int nt = 0; nt < 4; ++nt) {
            const int n   = cbase + nt * 16 + l15;
            const int kk  = ks * 32 + lg * 8;
            const int idx = n * F + (kk ^ ((n & 7) << 3));
            bhi[nt] = *(const bf16x8*)&lds_w[idx];
            blo[nt] = *(const bf16x8*)&lds_w[16384 + idx];
        }
        // 24 MFMAs; each acc updated 3x, 8 independent tiles between updates
        #pragma unroll
        for (int rt = 0; rt < 2; ++rt)
            #pragma unroll
            for (int nt = 0; nt < 4; ++nt)
                acc[rt][nt] = __builtin_amdgcn_mfma_f32_16x16x32_bf16(
                    ahi[rt], bhi[nt], acc[rt][nt], 0, 0, 0);
        #pragma unroll
        for (int rt = 0; rt < 2; ++rt)
            #pragma unroll
            for (int nt = 0; nt < 4; ++nt)
                acc[rt][nt] = __builtin_amdgcn_mfma_f32_16x16x32_bf16(
                    ahi[rt], blo[nt], acc[rt][nt], 0, 0, 0);
        #pragma unroll
        for (int rt = 0; rt < 2; ++rt)
            #pragma unroll
            for (int nt = 0; nt < 4; ++nt)
                acc[rt][nt] = __builtin_amdgcn_mfma_f32_16x16x32_bf16(
                    alo[rt], bhi[nt], acc[rt][nt], 0, 0, 0);
    }

    // epilogue: D col = lane&15, row = 4*(lane>>4)+reg; bf16 store
    #pragma unroll
    for (int rt = 0; rt < 2; ++rt)
        #pragma unroll
        for (int nt = 0; nt < 4; ++nt) {
            const int col = cbase + nt * 16 + l15;
            #pragma unroll
            for (int r = 0; r < 4; ++r) {
                const int row = rbase + rt * 16 + lg * 4 + r;
                outp[(size_t)row * F + col] = f2bf(acc[rt][nt][r]);
            }
        }
}

// ---------------------------------------------------------------------------
// Phase 2: out[p] = (1/sqrt(F)) * sum_f q[i,f] * w_ij[p,f] * k[j,f]
// UNCHANGED from the 486-µs kernel (near its BW floor): block owns 32 pairs;
// one wave stages 64 indices into LDS, each half-wave processes 4 pairs
// unrolled — 12 independent VMEM loads in flight per thread before any use.
// ---------------------------------------------------------------------------
__global__ __launch_bounds__(256) void edge_kernel(
    const float* __restrict__ w_ij,
    const int*   __restrict__ idx_i,
    const int*   __restrict__ idx_j,
    const unsigned short* __restrict__ q,
    const unsigned short* __restrict__ k,
    float* __restrict__ out)
{
    __shared__ int sidx[2 * PAIRS_PER_BLOCK];   // [0..31]=i, [32..63]=j

    const int p0 = blockIdx.x * PAIRS_PER_BLOCK;
    const int t  = threadIdx.x;

    if (t < 64) {
        sidx[t] = (t < 32) ? idx_i[p0 + t] : idx_j[p0 + t - 32];
    }
    __syncthreads();

    const int hw = t >> 5;   // half-wave id 0..7 -> pairs hw*4 .. hw*4+3
    const int l  = t & 31;   // lane within half-wave

    float4  wv[4];
    ushort4 qv[4], kv[4];
    #pragma unroll
    for (int u = 0; u < 4; ++u) {
        const int pp = hw * 4 + u;
        const int i = sidx[pp];
        const int j = sidx[PAIRS_PER_BLOCK + pp];
        wv[u] = *(const float4*)&w_ij[(size_t)(p0 + pp) * F + 4 * l];
        qv[u] = *(const ushort4*)&q[(size_t)i * F + 4 * l];
        kv[u] = *(const ushort4*)&k[(size_t)j * F + 4 * l];
    }

    #pragma unroll
    for (int u = 0; u < 4; ++u) {
        float s = bf2f(qv[u].x) * bf2f(kv[u].x) * wv[u].x
                + bf2f(qv[u].y) * bf2f(kv[u].y) * wv[u].y
                + bf2f(qv[u].z) * bf2f(kv[u].z) * wv[u].z
                + bf2f(qv[u].w) * bf2f(kv[u].w) * wv[u].w;
        s += __shfl_xor(s, 16);
        s += __shfl_xor(s, 8);
        s += __shfl_xor(s, 4);
        s += __shfl_xor(s, 2);
        s += __shfl_xor(s, 1);
        if (l == 0) out[p0 + hw * 4 + u] = s * 0.088388347648318447f;
    }
}

extern "C" void kernel_launch(void* const* d_in, const int* in_sizes, int n_in,
                              void* d_out, int out_size, void* d_ws, size_t ws_size,
                              hipStream_t stream) {
    const float* x     = (const float*)d_in[0];
    const float* w_ij  = (const float*)d_in[1];
    const int*   idx_i = (const int*)d_in[2];
    const int*   idx_j = (const int*)d_in[3];
    const float* Wq    = (const float*)d_in[4];
    const float* Wk    = (const float*)d_in[5];
    float* out = (float*)d_out;

    const int n_nodes = in_sizes[0] / F;   // 40000
    const int n_pairs = in_sizes[2];       // 640000

    unsigned short* q  = (unsigned short*)d_ws;
    unsigned short* k  = q + (size_t)n_nodes * F;
    unsigned short* wt = k + (size_t)n_nodes * F;   // 2 x 32768 shorts (128 KB)

    prep_w<<<128, 256, 0, stream>>>(Wq, Wk, wt);

    dim3 g1(n_nodes / 64, 2);   // 625 x 2, 64 rows/block
    proj_mfma<<<g1, 256, 0, stream>>>(x, wt, q, k);

    int g2 = n_pairs / PAIRS_PER_BLOCK;
    edge_kernel<<<g2, 256, 0, stream>>>(w_ij, idx_i, idx_j, q, k, out);
}